// Round 10
// baseline (120.372 us; speedup 1.0000x reference)
//
#include <hip/hip_runtime.h>
#include <hip/hip_bf16.h>
#include <stdint.h>

typedef __bf16 bf16;
typedef __bf16 bf16x8 __attribute__((ext_vector_type(8)));
typedef float f32x4 __attribute__((ext_vector_type(4)));
typedef float f32x16 __attribute__((ext_vector_type(16)));
typedef unsigned int u32;
typedef u32 u32x4 __attribute__((ext_vector_type(4)));

#define D_MODEL 1024
#define S_LEN 2048
#define NB 2
#define NH 16
#define DH 64

__device__ __forceinline__ void gload_lds16(const bf16* g, bf16* l) {
    auto gp = reinterpret_cast<const __attribute__((address_space(1))) unsigned int*>(
        reinterpret_cast<uintptr_t>(g));
    auto lp = reinterpret_cast<__attribute__((address_space(3))) unsigned int*>(
        reinterpret_cast<uintptr_t>(l));
    __builtin_amdgcn_global_load_lds(gp, lp, 16, 0, 0);
}

__device__ __forceinline__ u32 cvtpk(float lo, float hi) {
    u32 r; asm("v_cvt_pk_bf16_f32 %0, %1, %2" : "=v"(r) : "v"(lo), "v"(hi)); return r;
}
// NOTE: only safe when a and b hold DISTINCT values (round-7 post-mortem).
__device__ __forceinline__ void plswap(u32& a, u32& b) {
    asm("v_permlane32_swap_b32 %0, %1" : "+v"(a), "+v"(b));
}

// ---------------- f32 -> bf16 converter: q,k,v (4M each) + 4 weights (1M each) ------
__global__ __launch_bounds__(256)
void cvt_all(const float* __restrict__ q, const float* __restrict__ k,
             const float* __restrict__ v, const float* __restrict__ w0,
             const float* __restrict__ w1, const float* __restrict__ w2,
             const float* __restrict__ w3,
             bf16* __restrict__ oq, bf16* __restrict__ ok, bf16* __restrict__ ov,
             bf16* __restrict__ o0, bf16* __restrict__ o1, bf16* __restrict__ o2,
             bf16* __restrict__ o3)
{
    const int bid = blockIdx.x;
    const float* in; bf16* out; int local;
    if (bid < 6144) {
        int r = bid >> 11; local = bid & 2047;
        in  = (r == 0) ? q  : (r == 1) ? k  : v;
        out = (r == 0) ? oq : (r == 1) ? ok : ov;
    } else {
        int wb = bid - 6144;
        int r = wb >> 9; local = wb & 511;
        in  = (r == 0) ? w0 : (r == 1) ? w1 : (r == 2) ? w2 : w3;
        out = (r == 0) ? o0 : (r == 1) ? o1 : (r == 2) ? o2 : o3;
    }
    const size_t i = ((size_t)local * 256 + threadIdx.x) * 8;
    f32x4 x = *(const f32x4*)(in + i);
    f32x4 y = *(const f32x4*)(in + i + 4);
    bf16x8 o;
    #pragma unroll
    for (int j = 0; j < 4; ++j) { o[j] = (bf16)x[j]; o[4 + j] = (bf16)y[j]; }
    *(bf16x8*)(out + i) = o;
}

// ---------------- Fused QKV GEMM, 128x128 tile ----------------
// Q -> standard layout (pre-scaled). K -> fragment-packed KP[bh][kt32][db][lane] 16B
// chunks. V -> fragment-packed VP[bh][kt32][kb][dt][lane]. Pack via LDS round-trip.
__global__ __launch_bounds__(256, 2)
void gemm_qkv2(const bf16* __restrict__ Aq, const bf16* __restrict__ Ak, const bf16* __restrict__ Av,
               const bf16* __restrict__ Wq, const bf16* __restrict__ Wk, const bf16* __restrict__ Wv,
               const float* __restrict__ bq, const float* __restrict__ bk, const float* __restrict__ bv,
               bf16* __restrict__ Qo, bf16* __restrict__ KPo, bf16* __restrict__ VPo, float qscale)
{
    __shared__ __align__(16) char gsm[65536];    // As[2][8K] | Bs[2][8K]; Ts overlays
    bf16* As = (bf16*)gsm;
    bf16* Bs = (bf16*)(gsm + 32768);

    const int K = 1024;
    const int t = threadIdx.x, lane = t & 63, wid = t >> 6;
    const int nbn = 24;
    const int cpx = gridDim.x >> 3;              // 96
    const int bid = blockIdx.x;
    const int swz = (bid & 7) * cpx + (bid >> 3);
    const int bm0 = (swz / nbn) << 7;
    const int bn0 = (swz % nbn) << 7;
    const int sel = bn0 >> 10;                   // 0=Q 1=K 2=V
    const int nl  = bn0 & 1023;
    const bf16* Ap = (sel == 0) ? Aq : (sel == 1) ? Ak : Av;
    const bf16* Bp = (sel == 0) ? Wq : (sel == 1) ? Wk : Wv;
    const float* bias = (sel == 0) ? bq : (sel == 1) ? bk : bv;

    const int r16 = lane & 15, g = lane >> 4;
    const int wr = (wid >> 1) << 6;
    const int wc = (wid & 1) << 6;

    f32x4 acc[4][4] = {};

    auto stage = [&](int buf, int k0) {
        #pragma unroll
        for (int i = 0; i < 4; ++i) {
            int ch = wid * 256 + i * 64 + lane;
            int row = ch >> 3, c8 = ch & 7;
            int sc = c8 ^ (row & 7);
            gload_lds16(Ap + (size_t)(bm0 + row) * K + k0 + sc * 8, As + buf * 8192 + ch * 8);
            gload_lds16(Bp + (size_t)(nl + row) * K + k0 + sc * 8, Bs + buf * 8192 + ch * 8);
        }
    };

    int cur = 0;
    stage(0, 0);
    for (int k0 = 0; k0 < K; k0 += 64) {
        __syncthreads();
        if (k0 + 64 < K) stage(cur ^ 1, k0 + 64);
        #pragma unroll
        for (int ks = 0; ks < 2; ++ks) {
            const int cl = ks * 4 + g;
            bf16x8 af[4], bfr[4];
            #pragma unroll
            for (int mi = 0; mi < 4; ++mi) {
                int row = wr + mi * 16 + r16;
                af[mi] = *(const bf16x8*)((const char*)As + cur * 16384 + row * 128 + ((cl ^ (row & 7)) << 4));
            }
            #pragma unroll
            for (int ni = 0; ni < 4; ++ni) {
                int row = wc + ni * 16 + r16;
                bfr[ni] = *(const bf16x8*)((const char*)Bs + cur * 16384 + row * 128 + ((cl ^ (row & 7)) << 4));
            }
            #pragma unroll
            for (int mi = 0; mi < 4; ++mi)
                #pragma unroll
                for (int ni = 0; ni < 4; ++ni)
                    acc[mi][ni] = __builtin_amdgcn_mfma_f32_16x16x32_bf16(af[mi], bfr[ni], acc[mi][ni], 0, 0, 0);
        }
        cur ^= 1;
    }

    const int rb = g * 4;
    const int b2 = bm0 >> 11, kt0 = (bm0 & 2047) >> 5;
    if (sel == 0) {
        #pragma unroll
        for (int mi = 0; mi < 4; ++mi) {
            #pragma unroll
            for (int ni = 0; ni < 4; ++ni) {
                int cg = nl + wc + ni * 16 + r16;
                float bv = bias[cg];
                #pragma unroll
                for (int r = 0; r < 4; ++r) {
                    int rg = bm0 + wr + mi * 16 + rb + r;
                    Qo[(size_t)rg * 1024 + cg] = (bf16)((acc[mi][ni][r] + bv) * qscale);
                }
            }
        }
    } else if (sel == 1) {
        // K: Ts[s=128][d=136 pitch] then packed chunk store
        __syncthreads();
        bf16* Ts = (bf16*)gsm;
        #pragma unroll
        for (int mi = 0; mi < 4; ++mi)
            #pragma unroll
            for (int ni = 0; ni < 4; ++ni) {
                int dl = wc + ni * 16 + r16;
                float bv = bias[nl + dl];
                #pragma unroll
                for (int r = 0; r < 4; ++r) {
                    int sl = wr + mi * 16 + rb + r;
                    Ts[sl * 136 + dl] = (bf16)(acc[mi][ni][r] + bv);
                }
            }
        __syncthreads();
        #pragma unroll
        for (int i2 = 0; i2 < 8; ++i2) {
            int ch = t + i2 * 256;               // 0..2047
            int hloc = ch >> 10, rem = ch & 1023;
            int kt32loc = rem >> 8, db = (rem >> 6) & 3, ln = rem & 63;
            int srcs = kt32loc * 32 + (ln & 31);
            int srcd = hloc * 64 + db * 16 + (ln >> 5) * 8;
            bf16x8 v = *(const bf16x8*)&Ts[srcs * 136 + srcd];
            int bh2 = b2 * 16 + (nl >> 6) + hloc;
            int kt32 = kt0 + kt32loc;
            *(bf16x8*)(KPo + (((size_t)(bh2 * 64 + kt32) * 4 + db) * 64 + ln) * 8) = v;
        }
    } else {
        // V: Ts[d=128][s=136 pitch] then packed chunk store
        __syncthreads();
        bf16* Ts = (bf16*)gsm;
        #pragma unroll
        for (int mi = 0; mi < 4; ++mi)
            #pragma unroll
            for (int ni = 0; ni < 4; ++ni) {
                int dl = wc + ni * 16 + r16;
                float bv = bias[nl + dl];
                #pragma unroll
                for (int r = 0; r < 4; ++r) {
                    int sl = wr + mi * 16 + rb + r;
                    Ts[dl * 136 + sl] = (bf16)(acc[mi][ni][r] + bv);
                }
            }
        __syncthreads();
        #pragma unroll
        for (int i2 = 0; i2 < 8; ++i2) {
            int ch = t + i2 * 256;
            int hloc = ch >> 10, rem = ch & 1023;
            int kt32loc = rem >> 8, kb = (rem >> 7) & 1, dt = (rem >> 6) & 1, ln = rem & 63;
            int srcd = hloc * 64 + dt * 32 + (ln & 31);
            int srcs = kt32loc * 32 + kb * 16 + (ln >> 5) * 8;
            bf16x8 v = *(const bf16x8*)&Ts[srcd * 136 + srcs];
            int bh2 = b2 * 16 + (nl >> 6) + hloc;
            int kt32 = kt0 + kt32loc;
            *(bf16x8*)(VPo + ((((size_t)(bh2 * 64 + kt32) * 2 + kb) * 2 + dt) * 64 + ln) * 8) = v;
        }
    }
}

// ---------------- O-projection GEMM (f32 out), BM=128 BN=64 ----------------
__global__ __launch_bounds__(256)
void gemm_out(const bf16* __restrict__ Ap, const bf16* __restrict__ Bp,
              const float* __restrict__ bias, float* __restrict__ Cp)
{
    __shared__ __align__(16) bf16 As[2][128 * 64];
    __shared__ __align__(16) bf16 Bs[2][64 * 64];

    const int K = 1024, N = 1024;
    const int t = threadIdx.x, lane = t & 63, wid = t >> 6;
    const int nbn = 16;
    const int cpx = gridDim.x >> 3;
    const int bid = blockIdx.x;
    const int swz = (bid & 7) * cpx + (bid >> 3);
    const int bm0 = (swz / nbn) << 7;
    const int bn0 = (swz % nbn) << 6;
    const int r16 = lane & 15, g = lane >> 4;
    const int wr = (wid >> 1) << 6;
    const int wc = (wid & 1) << 5;

    f32x4 acc[4][2] = {};

    auto stage = [&](int buf, int k0) {
        #pragma unroll
        for (int i = 0; i < 4; ++i) {
            int ch = wid * 256 + i * 64 + lane;
            int row = ch >> 3, c8 = ch & 7;
            int sc = c8 ^ (row & 7);
            gload_lds16(Ap + (size_t)(bm0 + row) * K + k0 + sc * 8, &As[buf][ch * 8]);
        }
        #pragma unroll
        for (int i = 0; i < 2; ++i) {
            int ch = wid * 128 + i * 64 + lane;
            int row = ch >> 3, c8 = ch & 7;
            int sc = c8 ^ (row & 7);
            gload_lds16(Bp + (size_t)(bn0 + row) * K + k0 + sc * 8, &Bs[buf][ch * 8]);
        }
    };

    int cur = 0;
    stage(0, 0);
    for (int k0 = 0; k0 < K; k0 += 64) {
        __syncthreads();
        if (k0 + 64 < K) stage(cur ^ 1, k0 + 64);
        #pragma unroll
        for (int ks = 0; ks < 2; ++ks) {
            const int cl = ks * 4 + g;
            bf16x8 af[4], bfr[2];
            #pragma unroll
            for (int mi = 0; mi < 4; ++mi) {
                int row = wr + mi * 16 + r16;
                af[mi] = *(const bf16x8*)((const char*)&As[cur][0] + row * 128 + ((cl ^ (row & 7)) << 4));
            }
            #pragma unroll
            for (int ni = 0; ni < 2; ++ni) {
                int row = wc + ni * 16 + r16;
                bfr[ni] = *(const bf16x8*)((const char*)&Bs[cur][0] + row * 128 + ((cl ^ (row & 7)) << 4));
            }
            #pragma unroll
            for (int mi = 0; mi < 4; ++mi)
                #pragma unroll
                for (int ni = 0; ni < 2; ++ni)
                    acc[mi][ni] = __builtin_amdgcn_mfma_f32_16x16x32_bf16(af[mi], bfr[ni], acc[mi][ni], 0, 0, 0);
        }
        cur ^= 1;
    }

    const int rb = g * 4;
    #pragma unroll
    for (int mi = 0; mi < 4; ++mi) {
        #pragma unroll
        for (int ni = 0; ni < 2; ++ni) {
            int cg = bn0 + wc + ni * 16 + r16;
            float bv = bias[cg];
            #pragma unroll
            for (int r = 0; r < 4; ++r) {
                int rg = bm0 + wr + mi * 16 + rb + r;
                Cp[(size_t)rg * N + cg] = acc[mi][ni][r] + bv;
            }
        }
    }
}

// ---------------- Flash attention v9: fragment-packed, no LDS, no barriers ---------
// 4096 one-wave blocks = (bh, j 0..63, kh 0..1), heavy-first (j=63 first) -> HW
// backfill ~ LPT. Wave: 32 q-rows (subtile j), k-rounds [r0,r1) of 32-row tiles.
// K/V fragments loaded as contiguous 1KB packed chunks (100% sectors, L2-resident).
// Register double-buffer prefetch. Partials to workspace, merged by attn_merge9.
__global__ __launch_bounds__(64, 3)
void attn9(const bf16* __restrict__ Qp, const bf16* __restrict__ KP,
           const bf16* __restrict__ VP, bf16* __restrict__ Pws, float* __restrict__ MLws)
{
    const int lane = threadIdx.x;
    const int l31 = lane & 31, hh = lane >> 5;

    const int bid = blockIdx.x;              // 4096
    const int xcd = bid & 7, s = bid >> 3;   // s 0..511
    const int bh = xcd * 4 + (s & 3);        // 4 heads per XCD stream (L2-resident K/V)
    const int rest = s >> 2;                 // 0..127
    const int jd = rest >> 1, kh = rest & 1;
    const int j = 63 - jd;                   // heavy-first dispatch order
    const int b = bh >> 4, h = bh & 15;

    const int nA = (j + 2) >> 1;
    const int r0 = kh ? nA : 0;
    const int r1 = kh ? (j + 1) : nA;

    f32x16 oacc[2] = {};
    float mx = -1e30f, lsum = 0.f;

    if (r0 < r1) {
        bf16x8 qf[4];
        {
            const bf16* qrow = Qp + ((size_t)(b * S_LEN + j * 32 + l31)) * D_MODEL + h * DH + hh * 8;
            #pragma unroll
            for (int db = 0; db < 4; ++db) qf[db] = *(const bf16x8*)(qrow + db * 16);
        }

        const bf16* kp0 = KP + (size_t)bh * 131072 + lane * 8;   // 64 tiles * 2048 elems
        const bf16* vp0 = VP + (size_t)bh * 131072 + lane * 8;

        auto loadK = [&](int tt, bf16x8 (&kf)[4]) {
            const bf16* p = kp0 + (size_t)tt * 2048;
            #pragma unroll
            for (int db = 0; db < 4; ++db) kf[db] = *(const bf16x8*)(p + db * 512);
        };
        auto loadV = [&](int tt, bf16x8 (&vf)[4]) {
            const bf16* p = vp0 + (size_t)tt * 2048;
            #pragma unroll
            for (int q2 = 0; q2 < 4; ++q2) vf[q2] = *(const bf16x8*)(p + q2 * 512);
        };

        auto process = [&](const bf16x8 (&kf)[4], const bf16x8 (&vf)[4], bool diag) {
            f32x16 sacc = {};
            __builtin_amdgcn_s_setprio(1);
            #pragma unroll
            for (int db = 0; db < 4; ++db)
                sacc = __builtin_amdgcn_mfma_f32_32x32x16_bf16(kf[db], qf[db], sacc, 0, 0, 0);
            __builtin_amdgcn_s_setprio(0);
            if (diag) {
                #pragma unroll
                for (int r2 = 0; r2 < 16; ++r2) {
                    int cr = (r2 & 3) + 8 * (r2 >> 2) + 4 * hh;
                    if (cr > l31) sacc[r2] = -1e9f;
                }
            }
            float pm = -3e38f;
            #pragma unroll
            for (int r2 = 0; r2 < 16; ++r2) pm = fmaxf(pm, sacc[r2]);
            pm = fmaxf(pm, __shfl_xor(pm, 32));
            if (__any(pm > mx)) {
                float mnew = fmaxf(mx, pm);
                float al = __builtin_exp2f(mx - mnew);
                lsum *= al;
                #pragma unroll
                for (int dt = 0; dt < 2; ++dt)
                    #pragma unroll
                    for (int r2 = 0; r2 < 16; ++r2) oacc[dt][r2] *= al;
                mx = mnew;
            }
            float ts = 0.f;
            #pragma unroll
            for (int r2 = 0; r2 < 16; ++r2) {
                float p = __builtin_exp2f(sacc[r2] - mx);
                sacc[r2] = p;
                ts += p;
            }
            lsum += ts + __shfl_xor(ts, 32);
            #pragma unroll
            for (int kb = 0; kb < 2; ++kb) {
                u32 w0 = cvtpk(sacc[kb * 8 + 0], sacc[kb * 8 + 1]);
                u32 w2 = cvtpk(sacc[kb * 8 + 4], sacc[kb * 8 + 5]);
                u32 w1 = cvtpk(sacc[kb * 8 + 2], sacc[kb * 8 + 3]);
                u32 w3 = cvtpk(sacc[kb * 8 + 6], sacc[kb * 8 + 7]);
                plswap(w0, w2);
                plswap(w1, w3);
                u32x4 pw; pw[0] = w0; pw[1] = w1; pw[2] = w2; pw[3] = w3;
                bf16x8 pb = __builtin_bit_cast(bf16x8, pw);
                __builtin_amdgcn_s_setprio(1);
                #pragma unroll
                for (int dt = 0; dt < 2; ++dt)
                    oacc[dt] = __builtin_amdgcn_mfma_f32_32x32x16_bf16(vf[kb * 2 + dt], pb, oacc[dt], 0, 0, 0);
                __builtin_amdgcn_s_setprio(0);
            }
        };

        bf16x8 kfA[4], kfB[4], vfA[4], vfB[4];
        loadK(r0, kfA); loadV(r0, vfA);
        int r = r0;
        for (;;) {
            if (r + 1 < r1) { loadK(r + 1, kfB); loadV(r + 1, vfB); }
            process(kfA, vfA, r == j);
            if (++r >= r1) break;
            if (r + 1 < r1) { loadK(r + 1, kfA); loadV(r + 1, vfA); }
            process(kfB, vfB, r == j);
            if (++r >= r1) break;
        }
    }

    // ---- store partial: Pws[pid][q=32][d=64] bf16, MLws[pid][2][32]
    const int pid = (bh * 64 + j) * 2 + kh;
    bf16* pb2 = Pws + (size_t)pid * 2048;
    #pragma unroll
    for (int dt = 0; dt < 2; ++dt)
        #pragma unroll
        for (int r2 = 0; r2 < 16; r2 += 2) {
            int d = dt * 32 + (r2 & 3) + 8 * (r2 >> 2) + 4 * hh;
            *(u32*)(pb2 + l31 * 64 + d) = cvtpk(oacc[dt][r2], oacc[dt][r2 + 1]);
        }
    if (hh == 0) {
        MLws[pid * 64 + l31] = mx;
        MLws[pid * 64 + 32 + l31] = lsum;
    }
}

// ---------------- merge the two k-half partials -> Ob (standard layout) ------------
__global__ __launch_bounds__(256)
void attn_merge9(const bf16* __restrict__ Pws, const float* __restrict__ MLws,
                 bf16* __restrict__ Ob)
{
    const int mb = blockIdx.x;               // 2048 = 32bh x 64j
    const int bh = mb >> 6, j = mb & 63;
    const int b = bh >> 4, h = bh & 15;
    const int pidA = (bh * 64 + j) * 2, pidB = pidA + 1;

    const int t = threadIdx.x;
    const int q = t >> 3, c8 = t & 7;        // q 0..31, chunk 0..7
    const float mA = MLws[pidA * 64 + q], lA = MLws[pidA * 64 + 32 + q];
    const float mB = MLws[pidB * 64 + q], lB = MLws[pidB * 64 + 32 + q];
    const float m = fmaxf(mA, mB);
    float a0 = __builtin_exp2f(mA - m), a1 = __builtin_exp2f(mB - m);
    const float linv = 1.0f / (lA * a0 + lB * a1);
    a0 *= linv; a1 *= linv;
    const bf16* pA = Pws + (size_t)pidA * 2048 + q * 64 + c8 * 8;
    const bf16* pB = Pws + (size_t)pidB * 2048 + q * 64 + c8 * 8;
    bf16x8 va = *(const bf16x8*)pA;
    bf16x8 vb = *(const bf16x8*)pB;
    bf16x8 o;
    #pragma unroll
    for (int e = 0; e < 8; ++e)
        o[e] = (bf16)(a0 * (float)va[e] + a1 * (float)vb[e]);
    *(bf16x8*)(Ob + ((size_t)(b * S_LEN + j * 32 + q)) * D_MODEL + h * DH + c8 * 8) = o;
}

extern "C" void kernel_launch(void* const* d_in, const int* in_sizes, int n_in,
                              void* d_out, int out_size, void* d_ws, size_t ws_size,
                              hipStream_t stream)
{
    const float* query = (const float*)d_in[0];
    const float* key   = (const float*)d_in[1];
    const float* value = (const float*)d_in[2];
    // d_in[3] = mask: structurally causal (triu k=1) -> applied analytically
    const float* W_q = (const float*)d_in[4];
    const float* b_q = (const float*)d_in[5];
    const float* W_k = (const float*)d_in[6];
    const float* b_k = (const float*)d_in[7];
    const float* W_v = (const float*)d_in[8];
    const float* b_v = (const float*)d_in[9];
    const float* W_o = (const float*)d_in[10];
    const float* b_o = (const float*)d_in[11];

    char* w = (char*)d_ws;
    const size_t MB = 1 << 20;
    // [0,8) qbf | [8,16) kbf | [16,24) vbf   (dead after gemm_qkv2)
    // [24,32) Qb | [32,40) KP | [40,48) VP | [48,56) weights
    // attn9 partials overlay dead zone: Pws [0,16), MLws [16,17); merge writes Ob [17,25)
    // (Ob's tail overlaps Qb's head, but Qb is dead once attn9 completes.)
    bf16* qbf = (bf16*)(w);
    bf16* kbf = (bf16*)(w + 8 * MB);
    bf16* vbf = (bf16*)(w + 16 * MB);
    bf16* Qb  = (bf16*)(w + 24 * MB);         // pre-scaled by 0.125*log2(e)
    bf16* KP  = (bf16*)(w + 32 * MB);
    bf16* VP  = (bf16*)(w + 40 * MB);
    bf16* Wqb = (bf16*)(w + 48 * MB);
    bf16* Wkb = (bf16*)(w + 50 * MB);
    bf16* Wvb = (bf16*)(w + 52 * MB);
    bf16* Wob = (bf16*)(w + 54 * MB);
    bf16*  Pws  = (bf16*)(w);                 // 16MB (4096 x 4KB)
    float* MLws = (float*)(w + 16 * MB);      // 1MB
    bf16*  Ob   = (bf16*)(w + 17 * MB);       // 8MB

    dim3 blk(256);
    cvt_all<<<dim3(8192), blk, 0, stream>>>(query, key, value, W_q, W_k, W_v, W_o,
                                            qbf, kbf, vbf, Wqb, Wkb, Wvb, Wob);

    const float qscale = 0.125f * 1.4426950408889634f;   // 1/sqrt(64) * log2(e)
    gemm_qkv2<<<dim3(768), blk, 0, stream>>>(qbf, kbf, vbf, Wqb, Wkb, Wvb,
                                             b_q, b_k, b_v, Qb, KP, VP, qscale);

    attn9<<<dim3(4096), dim3(64), 0, stream>>>(Qb, KP, VP, Pws, MLws);
    attn_merge9<<<dim3(2048), blk, 0, stream>>>(Pws, MLws, Ob);

    gemm_out<<<dim3(512), blk, 0, stream>>>(Ob, Wob, b_o, (float*)d_out);
}